// Round 1
// baseline (104.989 us; speedup 1.0000x reference)
//
#include <hip/hip_runtime.h>
#include <hip/hip_bf16.h>

#define N_TOT 4096
#define D     512
#define BHALF 2048

// exp(2s) = 2^(s * 2*log2(e))
#define EXP2_SCALE 2.8853900817779268f

typedef __attribute__((ext_vector_type(8))) short short8;
typedef __attribute__((ext_vector_type(4))) float floatx4;

// ---------------- kernel 1: normalize rows, cast to bf16 ----------------
// grid = 4096 blocks, 128 threads; each thread handles one float4 (4 elems)
__global__ void normalize_kernel(const float* __restrict__ z_i,
                                 const float* __restrict__ z_j,
                                 short* __restrict__ zn) {
    int row = blockIdx.x;
    const float* src = (row < BHALF) ? (z_i + (size_t)row * D)
                                     : (z_j + (size_t)(row - BHALF) * D);
    int t = threadIdx.x;                       // 0..127
    float4 v = ((const float4*)src)[t];
    float ss = v.x*v.x + v.y*v.y + v.z*v.z + v.w*v.w;
    for (int off = 32; off > 0; off >>= 1) ss += __shfl_down(ss, off);
    __shared__ float red[2];
    if ((t & 63) == 0) red[t >> 6] = ss;
    __syncthreads();
    float total = red[0] + red[1];
    float inv = 1.0f / fmaxf(sqrtf(total), 1e-8f);
    short4 o;
    o.x = (short)__bfloat16_as_ushort(__float2bfloat16(v.x * inv));
    o.y = (short)__bfloat16_as_ushort(__float2bfloat16(v.y * inv));
    o.z = (short)__bfloat16_as_ushort(__float2bfloat16(v.z * inv));
    o.w = (short)__bfloat16_as_ushort(__float2bfloat16(v.w * inv));
    ((short4*)(zn + (size_t)row * D))[t] = o;
}

// ---------------- kernel 2: fused GEMM + exp + row-sum ----------------
// grid = (32, 32) blocks of 256 threads. Block (bi,bj) computes the
// 128x128 tile S[i0.., j0..] and accumulates exp(2S) row sums.
__launch_bounds__(256)
__global__ void gemm_fused(const short* __restrict__ zn,
                           float* __restrict__ rowsum,
                           float* __restrict__ sii,
                           float* __restrict__ spos) {
    __shared__ short At[128 * 32];
    __shared__ short Bt[128 * 32];
    const int i0 = blockIdx.x * 128;
    const int j0 = blockIdx.y * 128;
    const int t = threadIdx.x;
    const int lane = t & 63, wave = t >> 6;
    const int wm = wave & 1, wn = wave >> 1;     // 2x2 waves -> 64x64 each
    const int quad = lane >> 4, l16 = lane & 15;

    floatx4 acc[4][4] = {};

    for (int kt = 0; kt < D / 32; ++kt) {
        const int k0 = kt * 32;
        // stage A (rows i0..i0+127, k0..k0+31) and B (rows j0..) into LDS
        #pragma unroll
        for (int it = 0; it < 2; ++it) {
            int c  = t + it * 256;               // chunk 0..511 (16B each)
            int r  = c >> 2;
            int c8 = (c & 3) * 8;
            short8 av = *(const short8*)(zn + (size_t)(i0 + r) * D + k0 + c8);
            short8 bv = *(const short8*)(zn + (size_t)(j0 + r) * D + k0 + c8);
            *(short8*)(At + r * 32 + c8) = av;
            *(short8*)(Bt + r * 32 + c8) = bv;
        }
        __syncthreads();

        short8 af[4], bf[4];
        #pragma unroll
        for (int tm = 0; tm < 4; ++tm)
            af[tm] = *(const short8*)(At + (wm*64 + tm*16 + l16) * 32 + quad*8);
        #pragma unroll
        for (int tn = 0; tn < 4; ++tn)
            bf[tn] = *(const short8*)(Bt + (wn*64 + tn*16 + l16) * 32 + quad*8);
        #pragma unroll
        for (int tm = 0; tm < 4; ++tm)
            #pragma unroll
            for (int tn = 0; tn < 4; ++tn)
                acc[tm][tn] = __builtin_amdgcn_mfma_f32_16x16x32_bf16(
                    af[tm], bf[tn], acc[tm][tn], 0, 0, 0);
        __syncthreads();
    }

    // epilogue: e = exp(2s); capture diagonal + positive-pair entries;
    // per-row sum: reduce over tn in-register, over 16 lanes via shfl_xor.
    #pragma unroll
    for (int tm = 0; tm < 4; ++tm) {
        float rs[4] = {0.f, 0.f, 0.f, 0.f};
        #pragma unroll
        for (int tn = 0; tn < 4; ++tn) {
            int gj = j0 + wn*64 + tn*16 + l16;
            #pragma unroll
            for (int r = 0; r < 4; ++r) {
                int gi = i0 + wm*64 + tm*16 + quad*4 + r;
                float s = acc[tm][tn][r];
                float e = exp2f(s * EXP2_SCALE);
                rs[r] += e;
                if (gj == gi)            sii[gi]  = s;
                if (gj == (gi ^ BHALF))  spos[gi] = s;
            }
        }
        #pragma unroll
        for (int r = 0; r < 4; ++r) {
            float v = rs[r];
            v += __shfl_xor(v, 1);
            v += __shfl_xor(v, 2);
            v += __shfl_xor(v, 4);
            v += __shfl_xor(v, 8);
            if (l16 == 0) {
                int gi = i0 + wm*64 + tm*16 + quad*4 + r;
                atomicAdd(&rowsum[gi], v);
            }
        }
    }
}

// ---------------- kernel 3: final loss ----------------
__global__ void finalize_kernel(const float* __restrict__ rowsum,
                                const float* __restrict__ sii,
                                const float* __restrict__ spos,
                                float* __restrict__ out) {
    int t = threadIdx.x;                         // 256 threads, 1 block
    float acc = 0.f;
    for (int i = t; i < N_TOT; i += 256) {
        float sp = spos[i];
        float denom = rowsum[i] - exp2f(sii[i] * EXP2_SCALE)
                                + exp2f(sp     * EXP2_SCALE);
        acc += __logf(denom) - 2.0f * sp;
    }
    for (int off = 32; off > 0; off >>= 1) acc += __shfl_down(acc, off);
    __shared__ float red[4];
    if ((t & 63) == 0) red[t >> 6] = acc;
    __syncthreads();
    if (t == 0) out[0] = (red[0] + red[1] + red[2] + red[3]) / (float)N_TOT;
}

extern "C" void kernel_launch(void* const* d_in, const int* in_sizes, int n_in,
                              void* d_out, int out_size, void* d_ws, size_t ws_size,
                              hipStream_t stream) {
    const float* z_i = (const float*)d_in[0];
    const float* z_j = (const float*)d_in[1];
    float* out = (float*)d_out;

    char* ws = (char*)d_ws;
    short* zn     = (short*)ws;                                   // 4096*512*2 = 4 MB
    float* rowsum = (float*)(ws + (size_t)N_TOT * D * 2);         // 16 KB
    float* sii    = rowsum + N_TOT;                               // 16 KB
    float* spos   = sii + N_TOT;                                  // 16 KB

    hipMemsetAsync(rowsum, 0, N_TOT * sizeof(float), stream);

    normalize_kernel<<<N_TOT, 128, 0, stream>>>(z_i, z_j, zn);
    dim3 grid(N_TOT / 128, N_TOT / 128);
    gemm_fused<<<grid, 256, 0, stream>>>(zn, rowsum, sii, spos);
    finalize_kernel<<<1, 256, 0, stream>>>(rowsum, sii, spos, out);
}

// Round 2
// 98.494 us; speedup vs baseline: 1.0659x; 1.0659x over previous
//
#include <hip/hip_runtime.h>
#include <hip/hip_bf16.h>

#define N_TOT 4096
#define D     512
#define BHALF 2048

// exp(2s) = 2^(s * 2*log2(e))
#define EXP2_SCALE 2.8853900817779268f

typedef __attribute__((ext_vector_type(8))) short short8;
typedef __attribute__((ext_vector_type(4))) float floatx4;

#define AS_GLOBAL(p) ((const __attribute__((address_space(1))) void*)(p))
#define AS_LDS(p)    ((__attribute__((address_space(3))) void*)(p))

// ---------------- kernel 1: normalize rows, cast to bf16 (+ zero rowsum) ----
// grid = 4096 blocks, 128 threads; each thread handles one float4 (4 elems)
__global__ void normalize_kernel(const float* __restrict__ z_i,
                                 const float* __restrict__ z_j,
                                 short* __restrict__ zn,
                                 float* __restrict__ rowsum) {
    int row = blockIdx.x;
    const float* src = (row < BHALF) ? (z_i + (size_t)row * D)
                                     : (z_j + (size_t)(row - BHALF) * D);
    int t = threadIdx.x;                       // 0..127
    if (t == 0) rowsum[row] = 0.0f;            // replaces hipMemsetAsync
    float4 v = ((const float4*)src)[t];
    float ss = v.x*v.x + v.y*v.y + v.z*v.z + v.w*v.w;
    for (int off = 32; off > 0; off >>= 1) ss += __shfl_down(ss, off);
    __shared__ float red[2];
    if ((t & 63) == 0) red[t >> 6] = ss;
    __syncthreads();
    float total = red[0] + red[1];
    float inv = 1.0f / fmaxf(sqrtf(total), 1e-8f);
    short4 o;
    o.x = (short)__bfloat16_as_ushort(__float2bfloat16(v.x * inv));
    o.y = (short)__bfloat16_as_ushort(__float2bfloat16(v.y * inv));
    o.z = (short)__bfloat16_as_ushort(__float2bfloat16(v.z * inv));
    o.w = (short)__bfloat16_as_ushort(__float2bfloat16(v.w * inv));
    ((short4*)(zn + (size_t)row * D))[t] = o;
}

// ---------------- kernel 2: fused symmetric GEMM + exp + row-sum ----------
// Triangular grid: 528 blocks of 256 threads; block -> (bi, bj) with bj>=bi.
// Computes the 128x128 tile S[I,J]; adds exp(2S) row sums to rows I and
// (off-diagonal only) column sums to rows J (S symmetric).
__launch_bounds__(256)
__global__ void gemm_fused(const short* __restrict__ zn,
                           float* __restrict__ rowsum,
                           float* __restrict__ sii,
                           float* __restrict__ spos) {
    __shared__ short At[128 * 32];
    __shared__ short Bt[128 * 32];

    // triangular decode (scalar, <=32 iters)
    int b = blockIdx.x, bi = 0, rowlen = 32;
    while (b >= rowlen) { b -= rowlen; rowlen--; bi++; }
    const int bj = bi + b;
    const int i0 = bi * 128;
    const int j0 = bj * 128;

    const int t = threadIdx.x;
    const int lane = t & 63, wave = t >> 6;
    const int wm = wave & 1, wn = wave >> 1;     // 2x2 waves -> 64x64 each
    const int quad = lane >> 4, l16 = lane & 15;

    floatx4 acc[4][4] = {};

    // global_load_lds staging: each wave stages 32 rows of A and 32 of B
    // per k-tile, as 4 issues of (64 lanes x 16 B). Lane L covers row L>>2,
    // 16-byte chunk L&3 -> LDS offset exactly lane*16 from the wave base.
    const int sr = lane >> 2;                    // 0..15 row within chunk
    const int sc = (lane & 3) * 8;               // shorts within row
    const short* gA0 = zn + (size_t)(i0 + wave * 32 + sr)      * D + sc;
    const short* gA1 = zn + (size_t)(i0 + wave * 32 + 16 + sr) * D + sc;
    const short* gB0 = zn + (size_t)(j0 + wave * 32 + sr)      * D + sc;
    const short* gB1 = zn + (size_t)(j0 + wave * 32 + 16 + sr) * D + sc;
    short* lA0 = At + (wave * 32)      * 32;
    short* lA1 = At + (wave * 32 + 16) * 32;
    short* lB0 = Bt + (wave * 32)      * 32;
    short* lB1 = Bt + (wave * 32 + 16) * 32;

    for (int kt = 0; kt < D / 32; ++kt) {
        __builtin_amdgcn_global_load_lds(AS_GLOBAL(gA0), AS_LDS(lA0), 16, 0, 0);
        __builtin_amdgcn_global_load_lds(AS_GLOBAL(gA1), AS_LDS(lA1), 16, 0, 0);
        __builtin_amdgcn_global_load_lds(AS_GLOBAL(gB0), AS_LDS(lB0), 16, 0, 0);
        __builtin_amdgcn_global_load_lds(AS_GLOBAL(gB1), AS_LDS(lB1), 16, 0, 0);
        gA0 += 32; gA1 += 32; gB0 += 32; gB1 += 32;
        __syncthreads();

        short8 af[4], bf[4];
        #pragma unroll
        for (int tm = 0; tm < 4; ++tm)
            af[tm] = *(const short8*)(At + (wm*64 + tm*16 + l16) * 32 + quad*8);
        #pragma unroll
        for (int tn = 0; tn < 4; ++tn)
            bf[tn] = *(const short8*)(Bt + (wn*64 + tn*16 + l16) * 32 + quad*8);
        #pragma unroll
        for (int tm = 0; tm < 4; ++tm)
            #pragma unroll
            for (int tn = 0; tn < 4; ++tn)
                acc[tm][tn] = __builtin_amdgcn_mfma_f32_16x16x32_bf16(
                    af[tm], bf[tn], acc[tm][tn], 0, 0, 0);
        __syncthreads();
    }

    // epilogue: e = exp(2s). Row sums -> rows I; column sums -> rows J
    // (off-diagonal tiles only; diagonal tile's row sums already cover I==J).
    float cs[4] = {0.f, 0.f, 0.f, 0.f};         // per-tn column partials
    #pragma unroll
    for (int tm = 0; tm < 4; ++tm) {
        float rs[4] = {0.f, 0.f, 0.f, 0.f};
        #pragma unroll
        for (int tn = 0; tn < 4; ++tn) {
            int gj = j0 + wn*64 + tn*16 + l16;
            #pragma unroll
            for (int r = 0; r < 4; ++r) {
                int gi = i0 + wm*64 + tm*16 + quad*4 + r;
                float s = acc[tm][tn][r];
                float e = exp2f(s * EXP2_SCALE);
                rs[r] += e;
                cs[tn] += e;
                if (gj == gi)            sii[gi] = s;
                if (gj == (gi ^ BHALF)) { spos[gi] = s; spos[gj] = s; }
            }
        }
        #pragma unroll
        for (int r = 0; r < 4; ++r) {
            float v = rs[r];
            v += __shfl_xor(v, 1);
            v += __shfl_xor(v, 2);
            v += __shfl_xor(v, 4);
            v += __shfl_xor(v, 8);
            if (l16 == 0) {
                int gi = i0 + wm*64 + tm*16 + quad*4 + r;
                atomicAdd(&rowsum[gi], v);
            }
        }
    }
    if (bi != bj) {
        #pragma unroll
        for (int tn = 0; tn < 4; ++tn) {
            float v = cs[tn];
            v += __shfl_xor(v, 16);
            v += __shfl_xor(v, 32);
            if (quad == 0) {
                int gj = j0 + wn*64 + tn*16 + l16;
                atomicAdd(&rowsum[gj], v);
            }
        }
    }
}

// ---------------- kernel 3: final loss ----------------
__global__ void finalize_kernel(const float* __restrict__ rowsum,
                                const float* __restrict__ sii,
                                const float* __restrict__ spos,
                                float* __restrict__ out) {
    int t = threadIdx.x;                         // 256 threads, 1 block
    float acc = 0.f;
    for (int i = t; i < N_TOT; i += 256) {
        float sp = spos[i];
        float denom = rowsum[i] - exp2f(sii[i] * EXP2_SCALE)
                                + exp2f(sp     * EXP2_SCALE);
        acc += __logf(denom) - 2.0f * sp;
    }
    for (int off = 32; off > 0; off >>= 1) acc += __shfl_down(acc, off);
    __shared__ float red[4];
    if ((t & 63) == 0) red[t >> 6] = acc;
    __syncthreads();
    if (t == 0) out[0] = (red[0] + red[1] + red[2] + red[3]) / (float)N_TOT;
}

extern "C" void kernel_launch(void* const* d_in, const int* in_sizes, int n_in,
                              void* d_out, int out_size, void* d_ws, size_t ws_size,
                              hipStream_t stream) {
    const float* z_i = (const float*)d_in[0];
    const float* z_j = (const float*)d_in[1];
    float* out = (float*)d_out;

    char* ws = (char*)d_ws;
    short* zn     = (short*)ws;                                   // 4096*512*2 = 4 MB
    float* rowsum = (float*)(ws + (size_t)N_TOT * D * 2);         // 16 KB
    float* sii    = rowsum + N_TOT;                               // 16 KB
    float* spos   = sii + N_TOT;                                  // 16 KB

    normalize_kernel<<<N_TOT, 128, 0, stream>>>(z_i, z_j, zn, rowsum);
    gemm_fused<<<(32 * 33) / 2, 256, 0, stream>>>(zn, rowsum, sii, spos);
    finalize_kernel<<<1, 256, 0, stream>>>(rowsum, sii, spos, out);
}

// Round 3
// 94.006 us; speedup vs baseline: 1.1168x; 1.0477x over previous
//
#include <hip/hip_runtime.h>
#include <hip/hip_bf16.h>

#define N_TOT 4096
#define D     512
#define BHALF 2048

// exp(2s) = 2^(s * 2*log2(e))
#define EXP2_SCALE 2.8853900817779268f
// e^2 : exp(2*S_ii) for a normalized row (S_ii = 1 +- ~1e-4 in bf16; error in
// the final log is ~4e-7 -- negligible vs the 0.166 threshold)
#define E2 7.3890560989306495f

typedef __attribute__((ext_vector_type(8))) short short8;
typedef __attribute__((ext_vector_type(4))) float floatx4;

#define AS_GLOBAL(p) ((const __attribute__((address_space(1))) void*)(p))
#define AS_LDS(p)    ((__attribute__((address_space(3))) void*)(p))

// ---------------- kernel 1: normalize rows, cast to bf16 (+ zero rowsum) ----
// 1024 blocks x 256 threads; one 64-lane wave per row, no LDS, no barrier.
__global__ void normalize_kernel(const float* __restrict__ z_i,
                                 const float* __restrict__ z_j,
                                 short* __restrict__ zn,
                                 float* __restrict__ rowsum) {
    const int wave = threadIdx.x >> 6, lane = threadIdx.x & 63;
    const int row = blockIdx.x * 4 + wave;
    const float* src = (row < BHALF) ? (z_i + (size_t)row * D)
                                     : (z_j + (size_t)(row - BHALF) * D);
    if (lane == 0) rowsum[row] = 0.0f;         // replaces hipMemsetAsync
    float4 v0 = ((const float4*)src)[lane];
    float4 v1 = ((const float4*)src)[lane + 64];
    float ss = v0.x*v0.x + v0.y*v0.y + v0.z*v0.z + v0.w*v0.w
             + v1.x*v1.x + v1.y*v1.y + v1.z*v1.z + v1.w*v1.w;
    #pragma unroll
    for (int off = 32; off > 0; off >>= 1) ss += __shfl_xor(ss, off);
    float inv = 1.0f / fmaxf(sqrtf(ss), 1e-8f);
    short4 o0, o1;
    o0.x = (short)__bfloat16_as_ushort(__float2bfloat16(v0.x * inv));
    o0.y = (short)__bfloat16_as_ushort(__float2bfloat16(v0.y * inv));
    o0.z = (short)__bfloat16_as_ushort(__float2bfloat16(v0.z * inv));
    o0.w = (short)__bfloat16_as_ushort(__float2bfloat16(v0.w * inv));
    o1.x = (short)__bfloat16_as_ushort(__float2bfloat16(v1.x * inv));
    o1.y = (short)__bfloat16_as_ushort(__float2bfloat16(v1.y * inv));
    o1.z = (short)__bfloat16_as_ushort(__float2bfloat16(v1.z * inv));
    o1.w = (short)__bfloat16_as_ushort(__float2bfloat16(v1.w * inv));
    ((short4*)(zn + (size_t)row * D))[lane]      = o0;
    ((short4*)(zn + (size_t)row * D))[lane + 64] = o1;
}

// ---------------- kernel 2: fused symmetric GEMM + exp + row-sum ----------
// Triangular grid: 528 blocks of 256 threads; block -> (bi, bj), bj>=bi.
// Double-buffered LDS, global_load_lds prefetch, ONE barrier per k-iter.
__launch_bounds__(256)
__global__ void gemm_fused(const short* __restrict__ zn,
                           float* __restrict__ rowsum,
                           float* __restrict__ spos) {
    __shared__ short At[2][128 * 32];
    __shared__ short Bt[2][128 * 32];

    // triangular decode (scalar, <=32 iters)
    int b = blockIdx.x, bi = 0, rowlen = 32;
    while (b >= rowlen) { b -= rowlen; rowlen--; bi++; }
    const int bj = bi + b;
    const int i0 = bi * 128;
    const int j0 = bj * 128;

    const int t = threadIdx.x;
    const int lane = t & 63, wave = t >> 6;
    const int wm = wave & 1, wn = wave >> 1;     // 2x2 waves -> 64x64 each
    const int quad = lane >> 4, l16 = lane & 15;

    // staging addresses: lane L covers row L>>2, 16B chunk L&3 ->
    // LDS offset = wave base + lane*16 (contiguous; global_load_lds rule)
    const int sr = lane >> 2;
    const int sc = (lane & 3) * 8;
    const short* gA0 = zn + (size_t)(i0 + wave * 32 + sr)      * D + sc;
    const short* gA1 = zn + (size_t)(i0 + wave * 32 + 16 + sr) * D + sc;
    const short* gB0 = zn + (size_t)(j0 + wave * 32 + sr)      * D + sc;
    const short* gB1 = zn + (size_t)(j0 + wave * 32 + 16 + sr) * D + sc;
    const int lo0 = (wave * 32)      * 32;
    const int lo1 = (wave * 32 + 16) * 32;

    floatx4 acc[4][4] = {};

    // prologue: stage k-tile 0 into buffer 0
    __builtin_amdgcn_global_load_lds(AS_GLOBAL(gA0), AS_LDS(&At[0][lo0]), 16, 0, 0);
    __builtin_amdgcn_global_load_lds(AS_GLOBAL(gA1), AS_LDS(&At[0][lo1]), 16, 0, 0);
    __builtin_amdgcn_global_load_lds(AS_GLOBAL(gB0), AS_LDS(&Bt[0][lo0]), 16, 0, 0);
    __builtin_amdgcn_global_load_lds(AS_GLOBAL(gB1), AS_LDS(&Bt[0][lo1]), 16, 0, 0);

    for (int kt = 0; kt < 16; ++kt) {
        const int cur = kt & 1;
        // drains vmcnt -> buf[cur] ready; all waves done reading buf[1-cur]
        __syncthreads();
        if (kt < 15) {
            const int nxt = 1 - cur;
            const int ko = (kt + 1) * 32;
            __builtin_amdgcn_global_load_lds(AS_GLOBAL(gA0 + ko), AS_LDS(&At[nxt][lo0]), 16, 0, 0);
            __builtin_amdgcn_global_load_lds(AS_GLOBAL(gA1 + ko), AS_LDS(&At[nxt][lo1]), 16, 0, 0);
            __builtin_amdgcn_global_load_lds(AS_GLOBAL(gB0 + ko), AS_LDS(&Bt[nxt][lo0]), 16, 0, 0);
            __builtin_amdgcn_global_load_lds(AS_GLOBAL(gB1 + ko), AS_LDS(&Bt[nxt][lo1]), 16, 0, 0);
        }
        short8 af[4], bf[4];
        #pragma unroll
        for (int tm = 0; tm < 4; ++tm)
            af[tm] = *(const short8*)(&At[cur][(wm*64 + tm*16 + l16) * 32 + quad*8]);
        #pragma unroll
        for (int tn = 0; tn < 4; ++tn)
            bf[tn] = *(const short8*)(&Bt[cur][(wn*64 + tn*16 + l16) * 32 + quad*8]);
        #pragma unroll
        for (int tm = 0; tm < 4; ++tm)
            #pragma unroll
            for (int tn = 0; tn < 4; ++tn)
                acc[tm][tn] = __builtin_amdgcn_mfma_f32_16x16x32_bf16(
                    af[tm], bf[tn], acc[tm][tn], 0, 0, 0);
    }

    // epilogue: e = exp(2s). Row sums -> rows I; column sums -> rows J
    // (off-diagonal tiles; S symmetric). 2 atomics/row + 2 atomics/col.
    float cs[4] = {0.f, 0.f, 0.f, 0.f};
    #pragma unroll
    for (int tm = 0; tm < 4; ++tm) {
        float rs[4] = {0.f, 0.f, 0.f, 0.f};
        #pragma unroll
        for (int tn = 0; tn < 4; ++tn)
            #pragma unroll
            for (int r = 0; r < 4; ++r) {
                float e = exp2f(acc[tm][tn][r] * EXP2_SCALE);
                rs[r] += e;
                cs[tn] += e;
            }
        #pragma unroll
        for (int r = 0; r < 4; ++r) {
            float v = rs[r];
            v += __shfl_xor(v, 1);
            v += __shfl_xor(v, 2);
            v += __shfl_xor(v, 4);
            v += __shfl_xor(v, 8);
            if (l16 == 0) {
                int gi = i0 + wm*64 + tm*16 + quad*4 + r;
                atomicAdd(&rowsum[gi], v);
            }
        }
    }
    if (bi != bj) {
        #pragma unroll
        for (int tn = 0; tn < 4; ++tn) {
            float v = cs[tn];
            v += __shfl_xor(v, 16);
            v += __shfl_xor(v, 32);
            if (quad == 0) {
                int gj = j0 + wn*64 + tn*16 + l16;
                atomicAdd(&rowsum[gj], v);
            }
        }
    }
    // positive pairs (j = i + 2048) live exactly in blocks bj == bi+16
    if (bj == bi + 16) {
        #pragma unroll
        for (int tm = 0; tm < 4; ++tm)
            #pragma unroll
            for (int tn = 0; tn < 4; ++tn)
                #pragma unroll
                for (int r = 0; r < 4; ++r) {
                    int li = wm*64 + tm*16 + quad*4 + r;   // local row
                    int lj = wn*64 + tn*16 + l16;          // local col
                    if (li == lj) {
                        float s = acc[tm][tn][r];
                        spos[i0 + li]         = s;
                        spos[i0 + li + BHALF] = s;
                    }
                }
    }
}

// ---------------- kernel 3: final loss ----------------
__global__ void finalize_kernel(const float* __restrict__ rowsum,
                                const float* __restrict__ spos,
                                float* __restrict__ out) {
    int t = threadIdx.x;                         // 256 threads, 1 block
    float acc = 0.f;
    for (int i = t; i < N_TOT; i += 256) {
        float sp = spos[i];
        float denom = rowsum[i] - E2 + exp2f(sp * EXP2_SCALE);
        acc += __logf(denom) - 2.0f * sp;
    }
    for (int off = 32; off > 0; off >>= 1) acc += __shfl_down(acc, off);
    __shared__ float red[4];
    if ((t & 63) == 0) red[t >> 6] = acc;
    __syncthreads();
    if (t == 0) out[0] = (red[0] + red[1] + red[2] + red[3]) / (float)N_TOT;
}

extern "C" void kernel_launch(void* const* d_in, const int* in_sizes, int n_in,
                              void* d_out, int out_size, void* d_ws, size_t ws_size,
                              hipStream_t stream) {
    const float* z_i = (const float*)d_in[0];
    const float* z_j = (const float*)d_in[1];
    float* out = (float*)d_out;

    char* ws = (char*)d_ws;
    short* zn     = (short*)ws;                                   // 4 MB
    float* rowsum = (float*)(ws + (size_t)N_TOT * D * 2);         // 16 KB
    float* spos   = rowsum + N_TOT;                               // 16 KB

    normalize_kernel<<<N_TOT / 4, 256, 0, stream>>>(z_i, z_j, zn, rowsum);
    gemm_fused<<<(32 * 33) / 2, 256, 0, stream>>>(zn, rowsum, spos);
    finalize_kernel<<<1, 256, 0, stream>>>(rowsum, spos, out);
}